// Round 2
// baseline (189.176 us; speedup 1.0000x reference)
//
#include <hip/hip_runtime.h>
#include <hip/hip_fp16.h>
#include <stdint.h>

// ---------------------------------------------------------------------------
// ThreeBodyLayer fused kernel v8 (MI355X / gfx950)
//
// All-f16 MFMA pipeline, log2-domain softplus. Scale algebra: W1/b1 carry
// log2(e); W2 carries ln2*log2(e)=1; b2*log2(e); W3*ln2.
//
// v8 vs v7 (tb_fused 44.3us, VALU 55%, VGPR=32, 45% issue-idle):
//  - Phase-2 software pipeline: the t3 loop is fully unrolled into a static
//    2-deep prefetch schedule (two named u32x4 load sets, no runtime array
//    indexing). v7's VGPR=32 allocation forced serialized load->use chains,
//    exposing ~120cy LDS latency multiple times per unit. Now the next
//    unit's 4 ds_read_b128 issue before the current unit's ~600cy trans
//    chain, and the allocator is given a reason to hold ~56-64 VGPRs
//    (launch_bounds cap for 8 waves/SIMD is 64).
//  - Row-0 (core) fragments du0/du1 are loop-invariant: hoisted, 6->4
//    ds_read_b128 per unit.
//  - b2 bias folded into MFMA C-init (c0={b2,..}) instead of post-add.
//  - ws remains unused: the harness's 256MiB re-poison fill is unconditional
//    (v7 measured it; theory "fill tied to ws use" refuted) but zero-ws
//    still saves the prep launch.
// ---------------------------------------------------------------------------

typedef __attribute__((ext_vector_type(8))) _Float16 f16x8;
typedef __attribute__((ext_vector_type(2))) __fp16   fp16v2;   // cvt_pkrtz ret
typedef __attribute__((ext_vector_type(4))) float    f32x4;
typedef __attribute__((ext_vector_type(4))) unsigned int u32x4;

constexpr int   BPB       = 32;       // batch elems per block
constexpr int   NT        = 1024;     // 16 waves
constexpr int   T_STRIDE  = 1664;     // 13 rows * 128 B, chunk-swizzled
constexpr int   WT_OFF    = BPB * T_STRIDE;       // 53248
constexpr int   Y_OFF     = WT_OFF + 192 * 128;   // 77824
constexpr int   LDS_BYTES = Y_OFF + 128;          // 77952 -> 2 blocks/CU

constexpr float L2E = 1.4426950408889634f;
constexpr float LN2 = 0.6931471805599453f;

// PAIRS i/j packed 3 bits per pair (15 pairs)
constexpr unsigned long long I_BITS =
  (0ull<<0)|(0ull<<3)|(0ull<<6)|(0ull<<9)|(0ull<<12)|
  (1ull<<15)|(1ull<<18)|(1ull<<21)|(1ull<<24)|
  (2ull<<27)|(2ull<<30)|(2ull<<33)|
  (3ull<<36)|(3ull<<39)|(4ull<<42);
constexpr unsigned long long J_BITS =
  (1ull<<0)|(2ull<<3)|(3ull<<6)|(4ull<<9)|(5ull<<12)|
  (2ull<<15)|(3ull<<18)|(4ull<<21)|(5ull<<24)|
  (3ull<<27)|(4ull<<30)|(5ull<<33)|
  (4ull<<36)|(5ull<<39)|(5ull<<42);

__device__ __forceinline__ float sp2(float s) {       // log2(1+exp2(s))
  float t = __builtin_amdgcn_exp2f(s);
  return __builtin_amdgcn_logf(1.0f + t);             // v_log_f32 = log2
}

__device__ __forceinline__ __half2 h1pair(__half2 u, __half2 a, __half2 b,
                                          __half2 one2) {
  __half2 s = __hadd2(__hadd2(u, a), b);
  __half2 t = h2exp2(s);                              // |s|<~8 -> safe in f16
  return h2log2(__hadd2(one2, t));
}

union U4 { u32x4 u; __half2 h[4]; };
union AF { f16x8 v; __half2 h[4]; };

// Issue the 4 LDS reads for one phase-2 unit (row addresses from pair table).
__device__ __forceinline__ void load_unit(const char* Tb, int k0, int k1, int qv,
                                          u32x4& a0, u32x4& b0,
                                          u32x4& a1, u32x4& b1) {
  const int p  = qv >> 1;
  const int iv = (int)((I_BITS >> (3 * p)) & 7ull);
  const int jv = (int)((J_BITS >> (3 * p)) & 7ull);
  const int An = (qv & 1) ? jv : iv;
  const int Bn = (qv & 1) ? iv : jv;
  const char* TA = Tb + (1 + An) * 128;
  const char* TB = Tb + (7 + Bn) * 128;
  a0 = *(const u32x4*)(TA + k0);
  b0 = *(const u32x4*)(TB + k0);
  a1 = *(const u32x4*)(TA + k1);
  b1 = *(const u32x4*)(TB + k1);
}

// Softplus + L2 MFMA + epilogue for one unit. Loads are already in regs.
__device__ __forceinline__ void comp_unit(
    const u32x4& ra0, const u32x4& rb0, const u32x4& ra1, const u32x4& rb1,
    const __half2* uh0, const __half2* uh1,
    const f16x8 W2f[2][2], float b2v0, float b2v1,
    float w3v0, float w3v1, __half2 one2, float* yacc) {
  U4 da0, db0, da1, db1;
  da0.u = ra0; db0.u = rb0; da1.u = ra1; db1.u = rb1;
  AF A0, A1;
  #pragma unroll
  for (int w = 0; w < 4; ++w) A0.h[w] = h1pair(uh0[w], da0.h[w], db0.h[w], one2);
  #pragma unroll
  for (int w = 0; w < 4; ++w) A1.h[w] = h1pair(uh1[w], da1.h[w], db1.h[w], one2);

  f32x4 c0 = {b2v0, b2v0, b2v0, b2v0};                // bias as C-init
  f32x4 c1 = {b2v1, b2v1, b2v1, b2v1};
  c0 = __builtin_amdgcn_mfma_f32_16x16x32_f16(A0.v, W2f[0][0], c0, 0, 0, 0);
  c0 = __builtin_amdgcn_mfma_f32_16x16x32_f16(A1.v, W2f[0][1], c0, 0, 0, 0);
  c1 = __builtin_amdgcn_mfma_f32_16x16x32_f16(A0.v, W2f[1][0], c1, 0, 0, 0);
  c1 = __builtin_amdgcn_mfma_f32_16x16x32_f16(A1.v, W2f[1][1], c1, 0, 0, 0);

  #pragma unroll
  for (int reg = 0; reg < 4; ++reg)
    yacc[reg] += sp2(c0[reg]) * w3v0 + sp2(c1[reg]) * w3v1;
}

// ------------------------------ main kernel --------------------------------
__global__ __launch_bounds__(NT, 8)
void tb_fused(const float* __restrict__ core, const float* __restrict__ ligs,
              const float* __restrict__ W1,   const float* __restrict__ b1,
              const float* __restrict__ W2,   const float* __restrict__ b2,
              const float* __restrict__ W3,   const float* __restrict__ b3,
              float* __restrict__ out)
{
  extern __shared__ char smem[];
  const int tid  = (int)threadIdx.x;
  const int lane = tid & 63;
  const int ln   = lane & 15;        // fragment column
  const int qd   = lane >> 4;        // fragment quad
  const int swz  = ln & 7;           // XOR chunk swizzle key (= row&7 users)
  const int wv   = __builtin_amdgcn_readfirstlane(tid >> 6);  // 0..15
  const int b0   = (int)blockIdx.x * BPB;

  float* yred = (float*)(smem + Y_OFF);

  // ---- Phase-1 A-tile prefetch (cold HBM): issue before LDS staging ------
  const int xr = wv >> 1;
  const int mt = wv & 1;
  float4 fA[4];
  if (wv < 14) {
    const float* src = (xr == 0)
        ? (core + (size_t)(b0 + mt * 16 + ln) * 64)
        : (ligs + ((size_t)(b0 + mt * 16 + ln) * 6 + (size_t)(xr - 1)) * 64);
    #pragma unroll
    for (int ks = 0; ks < 2; ++ks) {
      fA[ks * 2 + 0] = *(const float4*)(src + ks * 32 + qd * 8);
      fA[ks * 2 + 1] = *(const float4*)(src + ks * 32 + qd * 8 + 4);
    }
  }

  // ---- stage W1T in-kernel: f32 [d=192][n=64] -> LDS f16, swizzled -------
  #pragma unroll
  for (int rep = 0; rep < 6; ++rep) {
    const int t  = tid + rep * NT;                    // 0..6143
    const int n  = t & 63;
    const int d0 = (t >> 6) << 1;                     // even, 0..190
    const float g0 = W1[(size_t)d0 * 64 + n] * L2E;
    const float g1 = W1[(size_t)(d0 + 1) * 64 + n] * L2E;
    const uint32_t pk = (uint32_t)__half_as_ushort(__float2half(g0))
                      | ((uint32_t)__half_as_ushort(__float2half(g1)) << 16);
    const int slab = d0 >> 6, dl = d0 & 63;
    *(uint32_t*)(smem + WT_OFF + (slab * 64 + n) * 128
                 + (((dl >> 3) ^ (n & 7)) << 4) + (dl & 7) * 2) = pk;
  }
  if (tid < BPB) yred[tid] = 0.0f;
  __syncthreads();                                    // barrier #1: W1T ready

  // ------------- Phase 1: 14 jobs = (xr 0..6) x (mt 0..1), 1 per wave -----
  if (wv < 14) {
    union AFr { f16x8 v; fp16v2 p[4]; } Afr[2];
    #pragma unroll
    for (int ks = 0; ks < 2; ++ks) {
      Afr[ks].p[0] = __builtin_amdgcn_cvt_pkrtz(fA[ks*2].x, fA[ks*2].y);
      Afr[ks].p[1] = __builtin_amdgcn_cvt_pkrtz(fA[ks*2].z, fA[ks*2].w);
      Afr[ks].p[2] = __builtin_amdgcn_cvt_pkrtz(fA[ks*2+1].x, fA[ks*2+1].y);
      Afr[ks].p[3] = __builtin_amdgcn_cvt_pkrtz(fA[ks*2+1].z, fA[ks*2+1].w);
    }

    const int sl_lo = (xr == 0) ? 0 : 1;
    const int sl_hi = (xr == 0) ? 0 : 2;
    #pragma unroll 1
    for (int sl = sl_lo; sl <= sl_hi; ++sl) {
      const int trow = (xr == 0) ? 0 : ((sl == 1) ? xr : 6 + xr);
      #pragma unroll
      for (int nt = 0; nt < 4; ++nt) {
        f32x4 c = {0.f, 0.f, 0.f, 0.f};
        #pragma unroll
        for (int ks = 0; ks < 2; ++ks) {
          // row = sl*64+nt*16+ln (row&7 == swz), chunk = ks*4+qd
          const f16x8 Bf = *(const f16x8*)(smem + WT_OFF
              + (sl * 64 + nt * 16 + ln) * 128 + ((((ks << 2) + qd) ^ swz) << 4));
          c = __builtin_amdgcn_mfma_f32_16x16x32_f16(Afr[ks].v, Bf, c, 0, 0, 0);
        }
        const float bias = (trow == 0) ? b1[nt * 16 + ln] * L2E : 0.0f;
        #pragma unroll
        for (int reg = 0; reg < 4; ++reg) {
          const int b = mt * 16 + qd * 4 + reg;       // C row = batch-local b
          // half index k = nt*16+ln: chunk = 2nt+(ln>>3) ^ (b&7), byte (ln&7)*2
          *(uint16_t*)(smem + (size_t)b * T_STRIDE + trow * 128
              + ((((nt << 1) + (ln >> 3)) ^ (b & 7)) << 4) + (ln & 7) * 2) =
              __half_as_ushort(__float2half(c[reg] + bias));
        }
      }
    }
  }

  // W2 B-frags + epilogue consts, straight from global (8KB, L1/L2-hot) —
  // overlaps Phase-1 tail.
  f16x8 W2f[2][2];
  #pragma unroll
  for (int nt = 0; nt < 2; ++nt) {
    #pragma unroll
    for (int ks = 0; ks < 2; ++ks) {
      union { f16x8 v; uint16_t u[8]; } w;
      #pragma unroll
      for (int j = 0; j < 8; ++j)
        w.u[j] = __half_as_ushort(__float2half(
            W2[(size_t)(ks * 32 + qd * 8 + j) * 32 + nt * 16 + ln]));
      W2f[nt][ks] = w.v;
    }
  }
  float b2v[2], w3v[2];
  #pragma unroll
  for (int nt = 0; nt < 2; ++nt) {
    b2v[nt] = b2[nt * 16 + ln] * L2E;
    w3v[nt] = W3[nt * 16 + ln] * LN2;
  }

  __syncthreads();                                    // barrier #2: T ready

  // ------------- Phase 2: 60 units (30 q x 2 mt) over 16 waves ------------
  // Static 2-deep pipeline: units q = qr, qr+8, qr+16, (qr+24 if qr<6).
  const int mtw = wv & 1;
  const int qr  = wv >> 1;                            // 0..7
  const __half2 one2 = __float2half2_rn(1.0f);
  const char* Tb = smem + (size_t)(mtw * 16 + ln) * T_STRIDE;
  const int k0 = ((qd)     ^ swz) << 4;               // chunk qd   (ks=0)
  const int k1 = ((qd + 4) ^ swz) << 4;               // chunk qd+4 (ks=1)

  // Row 0 (core pre-activations) is unit-invariant: hoist its 2 reads.
  U4 du0, du1;
  du0.u = *(const u32x4*)(Tb + k0);
  du1.u = *(const u32x4*)(Tb + k1);
  __half2 uh0[4], uh1[4];
  #pragma unroll
  for (int w = 0; w < 4; ++w) { uh0[w] = du0.h[w]; uh1[w] = du1.h[w]; }

  float yacc[4] = {0.f, 0.f, 0.f, 0.f};

  u32x4 Aa0, Ab0, Aa1, Ab1;                           // pipeline set A
  u32x4 Ba0, Bb0, Ba1, Bb1;                           // pipeline set B

  load_unit(Tb, k0, k1, qr,      Aa0, Ab0, Aa1, Ab1);
  load_unit(Tb, k0, k1, qr + 8,  Ba0, Bb0, Ba1, Bb1);

  comp_unit(Aa0, Ab0, Aa1, Ab1, uh0, uh1, W2f,
            b2v[0], b2v[1], w3v[0], w3v[1], one2, yacc);   // unit qr
  load_unit(Tb, k0, k1, qr + 16, Aa0, Ab0, Aa1, Ab1);

  comp_unit(Ba0, Bb0, Ba1, Bb1, uh0, uh1, W2f,
            b2v[0], b2v[1], w3v[0], w3v[1], one2, yacc);   // unit qr+8
  const bool has3 = (qr < 6);                              // wave-uniform
  if (has3) load_unit(Tb, k0, k1, qr + 24, Ba0, Bb0, Ba1, Bb1);

  comp_unit(Aa0, Ab0, Aa1, Ab1, uh0, uh1, W2f,
            b2v[0], b2v[1], w3v[0], w3v[1], one2, yacc);   // unit qr+16
  if (has3)
    comp_unit(Ba0, Bb0, Ba1, Bb1, uh0, uh1, W2f,
              b2v[0], b2v[1], w3v[0], w3v[1], one2, yacc); // unit qr+24

  // reduce over the 16 fragment columns (ln) inside each quad group
  #pragma unroll
  for (int reg = 0; reg < 4; ++reg) {
    float v = yacc[reg];
    v += __shfl_xor(v, 1);
    v += __shfl_xor(v, 2);
    v += __shfl_xor(v, 4);
    v += __shfl_xor(v, 8);
    yacc[reg] = v;
  }
  if (ln == 0) {
    #pragma unroll
    for (int reg = 0; reg < 4; ++reg)
      atomicAdd(&yred[mtw * 16 + qd * 4 + reg], yacc[reg]);
  }
  __syncthreads();
  if (tid < BPB) out[b0 + tid] = 0.5f * yred[tid] + 15.0f * b3[0];
}

extern "C" void kernel_launch(void* const* d_in, const int* in_sizes, int n_in,
                              void* d_out, int out_size, void* d_ws, size_t ws_size,
                              hipStream_t stream) {
  (void)d_ws; (void)ws_size;                // workspace intentionally unused
  const float* core = (const float*)d_in[0];
  const float* ligs = (const float*)d_in[1];
  const float* W1   = (const float*)d_in[2];
  const float* b1   = (const float*)d_in[3];
  const float* W2   = (const float*)d_in[4];
  const float* b2   = (const float*)d_in[5];
  const float* W3   = (const float*)d_in[6];
  const float* b3   = (const float*)d_in[7];
  float* out = (float*)d_out;

  const int B = in_sizes[0] / 64;           // 32768
  const int grid = B / BPB;                 // 1024

  (void)hipFuncSetAttribute((const void*)tb_fused,
                            hipFuncAttributeMaxDynamicSharedMemorySize, LDS_BYTES);
  tb_fused<<<dim3(grid), dim3(NT), LDS_BYTES, stream>>>(
      core, ligs, W1, b1, W2, b2, W3, b3, out);
}

// Round 3
// 131.071 us; speedup vs baseline: 1.4433x; 1.4433x over previous
//
#include <hip/hip_runtime.h>
#include <hip/hip_fp16.h>
#include <stdint.h>

// ---------------------------------------------------------------------------
// ThreeBodyLayer fused kernel v9 (MI355X / gfx950)
//
// All-f16 MFMA pipeline, log2-domain softplus. Scale algebra: W1/b1 carry
// log2(e); W2 carries ln2*log2(e)=1; b2*log2(e); W3*ln2.
//
// v9 vs v8 (spill disaster: helper fns passed locals by pointer -> scratch,
// WRITE_SIZE 227MB) and v7 (44us, VALU 55%, occ 66%, 2 fat blocks/CU in
// barrier lockstep):
//  - REVERT to v7's fully-inline structure. NO helper functions taking
//    references/pointers to locals; all arrays constant-indexed.
//  - BPB 32->16, NT 1024->512, LDS 78KB->50.1KB => 3 blocks/CU (24 waves/CU
//    vs 21). More independent blocks fill barrier-convergence bubbles
//    (phase-1 imbalance, post-barrier LDS burst) with other blocks' work.
//  - Phase 1 rebalanced: 13 T-row jobs (core + 12 lig slabs) over 8 waves,
//    every wave active (v7: waves 14/15 idle, 2:1 imbalance).
//  - Kept from v8 (inline, proven numerics): row-0 du loads hoisted out of
//    the phase-2 loop (6->4 ds_read_b128/unit); b2 folded into MFMA C-init.
//  - ws unused (256MiB harness re-poison fill is unconditional; v7 measured).
// ---------------------------------------------------------------------------

typedef __attribute__((ext_vector_type(8))) _Float16 f16x8;
typedef __attribute__((ext_vector_type(2))) __fp16   fp16v2;   // cvt_pkrtz ret
typedef __attribute__((ext_vector_type(4))) float    f32x4;
typedef __attribute__((ext_vector_type(4))) unsigned int u32x4;

constexpr int   BPB       = 16;       // batch elems per block
constexpr int   NT        = 512;      // 8 waves
constexpr int   T_STRIDE  = 1664;     // 13 rows * 128 B, chunk-swizzled
constexpr int   WT_OFF    = BPB * T_STRIDE;       // 26624
constexpr int   Y_OFF     = WT_OFF + 192 * 128;   // 51200
constexpr int   LDS_BYTES = Y_OFF + 128;          // 51328 -> 3 blocks/CU

constexpr float L2E = 1.4426950408889634f;
constexpr float LN2 = 0.6931471805599453f;

// PAIRS i/j packed 3 bits per pair (15 pairs)
constexpr unsigned long long I_BITS =
  (0ull<<0)|(0ull<<3)|(0ull<<6)|(0ull<<9)|(0ull<<12)|
  (1ull<<15)|(1ull<<18)|(1ull<<21)|(1ull<<24)|
  (2ull<<27)|(2ull<<30)|(2ull<<33)|
  (3ull<<36)|(3ull<<39)|(4ull<<42);
constexpr unsigned long long J_BITS =
  (1ull<<0)|(2ull<<3)|(3ull<<6)|(4ull<<9)|(5ull<<12)|
  (2ull<<15)|(3ull<<18)|(4ull<<21)|(5ull<<24)|
  (3ull<<27)|(4ull<<30)|(5ull<<33)|
  (4ull<<36)|(5ull<<39)|(5ull<<42);

__device__ __forceinline__ float sp2(float s) {       // log2(1+exp2(s))
  float t = __builtin_amdgcn_exp2f(s);
  return __builtin_amdgcn_logf(1.0f + t);             // v_log_f32 = log2
}

__device__ __forceinline__ __half2 h1pair(__half2 u, __half2 a, __half2 b,
                                          __half2 one2) {
  __half2 s = __hadd2(__hadd2(u, a), b);
  __half2 t = h2exp2(s);                              // |s|<~8 -> safe in f16
  return h2log2(__hadd2(one2, t));
}

// ------------------------------ main kernel --------------------------------
__global__ __launch_bounds__(NT, 6)
void tb_fused(const float* __restrict__ core, const float* __restrict__ ligs,
              const float* __restrict__ W1,   const float* __restrict__ b1,
              const float* __restrict__ W2,   const float* __restrict__ b2,
              const float* __restrict__ W3,   const float* __restrict__ b3,
              float* __restrict__ out)
{
  extern __shared__ char smem[];
  const int tid  = (int)threadIdx.x;
  const int lane = tid & 63;
  const int ln   = lane & 15;        // fragment column
  const int qd   = lane >> 4;        // fragment quad
  const int swz  = ln & 7;           // XOR chunk swizzle key (= row&7 users)
  const int wv   = __builtin_amdgcn_readfirstlane(tid >> 6);  // 0..7
  const int b0   = (int)blockIdx.x * BPB;

  float* yred = (float*)(smem + Y_OFF);

  // ---- Phase-1 job table: 13 T-rows (0=core, 1..6=slab1, 7..12=slab2) ----
  // Wave w owns rows t1=w and t2=w+8 (t2 valid for w<5). Every wave active.
  const int t1 = wv;
  const int t2 = wv + 8;
  const bool j2 = (t2 < 13);

  // A-tile global prefetch (cold HBM): issue before LDS staging.
  float4 fA[2][4];
  {
    const int xr = (t1 == 0) ? 0 : (t1 <= 6 ? t1 : t1 - 6);
    const float* src = (xr == 0)
        ? (core + (size_t)(b0 + ln) * 64)
        : (ligs + ((size_t)(b0 + ln) * 6 + (size_t)(xr - 1)) * 64);
    #pragma unroll
    for (int ks = 0; ks < 2; ++ks) {
      fA[0][ks * 2 + 0] = *(const float4*)(src + ks * 32 + qd * 8);
      fA[0][ks * 2 + 1] = *(const float4*)(src + ks * 32 + qd * 8 + 4);
    }
  }
  if (j2) {
    const int xr = t2 - 6;                            // 2..6, slab 2
    const float* src = ligs + ((size_t)(b0 + ln) * 6 + (size_t)(xr - 1)) * 64;
    #pragma unroll
    for (int ks = 0; ks < 2; ++ks) {
      fA[1][ks * 2 + 0] = *(const float4*)(src + ks * 32 + qd * 8);
      fA[1][ks * 2 + 1] = *(const float4*)(src + ks * 32 + qd * 8 + 4);
    }
  }

  // ---- stage W1T in-kernel: f32 [d=192][n=64] -> LDS f16, swizzled -------
  #pragma unroll
  for (int rep = 0; rep < 12; ++rep) {
    const int t  = tid + rep * NT;                    // 0..6143
    const int n  = t & 63;
    const int d0 = (t >> 6) << 1;                     // even, 0..190
    const float g0 = W1[(size_t)d0 * 64 + n] * L2E;
    const float g1 = W1[(size_t)(d0 + 1) * 64 + n] * L2E;
    const uint32_t pk = (uint32_t)__half_as_ushort(__float2half(g0))
                      | ((uint32_t)__half_as_ushort(__float2half(g1)) << 16);
    const int slab = d0 >> 6, dl = d0 & 63;
    *(uint32_t*)(smem + WT_OFF + (slab * 64 + n) * 128
                 + (((dl >> 3) ^ (n & 7)) << 4) + (dl & 7) * 2) = pk;
  }

  // Convert A tiles to f16 frags while staging loads drain.
  union AFr { f16x8 v; fp16v2 p[4]; } Afr[2][2];
  #pragma unroll
  for (int jj = 0; jj < 2; ++jj) {
    if (jj == 1 && !j2) break;                        // wave-uniform
    #pragma unroll
    for (int ks = 0; ks < 2; ++ks) {
      Afr[jj][ks].p[0] = __builtin_amdgcn_cvt_pkrtz(fA[jj][ks*2].x, fA[jj][ks*2].y);
      Afr[jj][ks].p[1] = __builtin_amdgcn_cvt_pkrtz(fA[jj][ks*2].z, fA[jj][ks*2].w);
      Afr[jj][ks].p[2] = __builtin_amdgcn_cvt_pkrtz(fA[jj][ks*2+1].x, fA[jj][ks*2+1].y);
      Afr[jj][ks].p[3] = __builtin_amdgcn_cvt_pkrtz(fA[jj][ks*2+1].z, fA[jj][ks*2+1].w);
    }
  }
  if (tid < BPB) yred[tid] = 0.0f;
  __syncthreads();                                    // barrier #1: W1T ready

  // ------------- Phase 1: up to 2 T-row jobs per wave ---------------------
  #pragma unroll
  for (int jj = 0; jj < 2; ++jj) {
    if (jj == 1 && !j2) break;                        // wave-uniform
    const int t  = (jj == 0) ? t1 : t2;               // trow
    const int sl = (t == 0) ? 0 : (t <= 6 ? 1 : 2);
    #pragma unroll
    for (int nt = 0; nt < 4; ++nt) {
      f32x4 c = {0.f, 0.f, 0.f, 0.f};
      #pragma unroll
      for (int ks = 0; ks < 2; ++ks) {
        // row = sl*64+nt*16+ln (row&7 == swz), chunk = ks*4+qd
        const f16x8 Bf = *(const f16x8*)(smem + WT_OFF
            + (sl * 64 + nt * 16 + ln) * 128 + ((((ks << 2) + qd) ^ swz) << 4));
        c = __builtin_amdgcn_mfma_f32_16x16x32_f16(Afr[jj][ks].v, Bf, c, 0, 0, 0);
      }
      const float bias = (t == 0) ? b1[nt * 16 + ln] * L2E : 0.0f;
      #pragma unroll
      for (int reg = 0; reg < 4; ++reg) {
        const int b = qd * 4 + reg;                   // C row = batch-local b
        // half index k = nt*16+ln: chunk = 2nt+(ln>>3) ^ (b&7), byte (ln&7)*2
        *(uint16_t*)(smem + (size_t)b * T_STRIDE + t * 128
            + ((((nt << 1) + (ln >> 3)) ^ (b & 7)) << 4) + (ln & 7) * 2) =
            __half_as_ushort(__float2half(c[reg] + bias));
      }
    }
  }

  // W2 B-frags + epilogue consts, straight from global (8KB, L1/L2-hot) —
  // overlaps Phase-1 tail.
  f16x8 W2f[2][2];
  #pragma unroll
  for (int nt = 0; nt < 2; ++nt) {
    #pragma unroll
    for (int ks = 0; ks < 2; ++ks) {
      union { f16x8 v; uint16_t u[8]; } w;
      #pragma unroll
      for (int j = 0; j < 8; ++j)
        w.u[j] = __half_as_ushort(__float2half(
            W2[(size_t)(ks * 32 + qd * 8 + j) * 32 + nt * 16 + ln]));
      W2f[nt][ks] = w.v;
    }
  }
  float b2v[2], w3v[2];
  #pragma unroll
  for (int nt = 0; nt < 2; ++nt) {
    b2v[nt] = b2[nt * 16 + ln] * L2E;
    w3v[nt] = W3[nt * 16 + ln] * LN2;
  }

  __syncthreads();                                    // barrier #2: T ready

  // ------------- Phase 2: 30 q-units over 8 waves -------------------------
  const int qr = wv;                                  // 0..7
  const __half2 one2 = __float2half2_rn(1.0f);
  const char* Tb = smem + (size_t)ln * T_STRIDE;
  const int k0 = ((qd)     ^ swz) << 4;               // chunk qd   (ks=0)
  const int k1 = ((qd + 4) ^ swz) << 4;               // chunk qd+4 (ks=1)

  union U4 { u32x4 u; __half2 h[4]; };

  // Row 0 (core pre-activations) is unit-invariant: hoist its 2 reads.
  U4 du0, du1;
  du0.u = *(const u32x4*)(Tb + k0);
  du1.u = *(const u32x4*)(Tb + k1);

  float yacc[4] = {0.f, 0.f, 0.f, 0.f};

  #pragma unroll 2
  for (int t3 = 0; t3 < 4; ++t3) {
    const int q = qr + 8 * t3;
    if (q >= 30) break;                               // wave-uniform
    const int p  = q >> 1;
    const int iv = (int)((I_BITS >> (3 * p)) & 7ull);
    const int jv = (int)((J_BITS >> (3 * p)) & 7ull);
    const int An = (q & 1) ? jv : iv;
    const int Bn = (q & 1) ? iv : jv;
    const char* TA = Tb + (1 + An) * 128;
    const char* TB = Tb + (7 + Bn) * 128;

    U4 da0, db0, da1, db1;
    da0.u = *(const u32x4*)(TA + k0);
    db0.u = *(const u32x4*)(TB + k0);
    da1.u = *(const u32x4*)(TA + k1);
    db1.u = *(const u32x4*)(TB + k1);

    union { f16x8 v; __half2 h[4]; } A0, A1;
    #pragma unroll
    for (int w = 0; w < 4; ++w) A0.h[w] = h1pair(du0.h[w], da0.h[w], db0.h[w], one2);
    #pragma unroll
    for (int w = 0; w < 4; ++w) A1.h[w] = h1pair(du1.h[w], da1.h[w], db1.h[w], one2);

    f32x4 c0 = {b2v[0], b2v[0], b2v[0], b2v[0]};      // bias as C-init
    f32x4 c1 = {b2v[1], b2v[1], b2v[1], b2v[1]};
    c0 = __builtin_amdgcn_mfma_f32_16x16x32_f16(A0.v, W2f[0][0], c0, 0, 0, 0);
    c0 = __builtin_amdgcn_mfma_f32_16x16x32_f16(A1.v, W2f[0][1], c0, 0, 0, 0);
    c1 = __builtin_amdgcn_mfma_f32_16x16x32_f16(A0.v, W2f[1][0], c1, 0, 0, 0);
    c1 = __builtin_amdgcn_mfma_f32_16x16x32_f16(A1.v, W2f[1][1], c1, 0, 0, 0);

    #pragma unroll
    for (int reg = 0; reg < 4; ++reg) {
      yacc[reg] += sp2(c0[reg]) * w3v[0] + sp2(c1[reg]) * w3v[1];
    }
  }

  // reduce over the 16 fragment columns (ln) inside each quad group
  #pragma unroll
  for (int reg = 0; reg < 4; ++reg) {
    float v = yacc[reg];
    v += __shfl_xor(v, 1);
    v += __shfl_xor(v, 2);
    v += __shfl_xor(v, 4);
    v += __shfl_xor(v, 8);
    yacc[reg] = v;
  }
  if (ln == 0) {
    #pragma unroll
    for (int reg = 0; reg < 4; ++reg)
      atomicAdd(&yred[qd * 4 + reg], yacc[reg]);
  }
  __syncthreads();
  if (tid < BPB) out[b0 + tid] = 0.5f * yred[tid] + 15.0f * b3[0];
}

extern "C" void kernel_launch(void* const* d_in, const int* in_sizes, int n_in,
                              void* d_out, int out_size, void* d_ws, size_t ws_size,
                              hipStream_t stream) {
  (void)d_ws; (void)ws_size;                // workspace intentionally unused
  const float* core = (const float*)d_in[0];
  const float* ligs = (const float*)d_in[1];
  const float* W1   = (const float*)d_in[2];
  const float* b1   = (const float*)d_in[3];
  const float* W2   = (const float*)d_in[4];
  const float* b2   = (const float*)d_in[5];
  const float* W3   = (const float*)d_in[6];
  const float* b3   = (const float*)d_in[7];
  float* out = (float*)d_out;

  const int B = in_sizes[0] / 64;           // 32768
  const int grid = B / BPB;                 // 2048

  (void)hipFuncSetAttribute((const void*)tb_fused,
                            hipFuncAttributeMaxDynamicSharedMemorySize, LDS_BYTES);
  tb_fused<<<dim3(grid), dim3(NT), LDS_BYTES, stream>>>(
      core, ligs, W1, b1, W2, b2, W3, b3, out);
}

// Round 4
// 126.284 us; speedup vs baseline: 1.4980x; 1.0379x over previous
//
#include <hip/hip_runtime.h>
#include <hip/hip_fp16.h>
#include <stdint.h>

// ---------------------------------------------------------------------------
// ThreeBodyLayer fused kernel v10 (MI355X / gfx950)
//
// All-f16 MFMA pipeline, log2-domain softplus. Scale algebra: W1/b1 carry
// log2(e); W2 carries ln2*log2(e)=1; b2*log2(e); W3*ln2.
//
// v10 vs v9 (48-52us: 24 waves/CU < v7's 32, revert shape) and v7 (44.3us,
// VALU-issue-bound: ~24us of VALU, ~1/3 of it overhead):
//  - ws prep kernel returns (v7 MEASURED the 256MiB ws re-poison fill is
//    unconditional -> using ws is free). prep pre-converts:
//      * W1T f16 PRE-SWIZZLED in the exact LDS image order -> block staging
//        is a plain uint4 copy (was: 12 f32 loads + mul + cvt + pack /thread)
//      * W2 as f16 frag layout -> 4 dwordx4 loads/lane (was 32 scalar + cvt)
//      * b1*L2E, b2*L2E, W3*LN2 as f32
//  - Phase-1 OPERAND SWAP: mfma(A=W1frag, B=xfrag) -> D row=n, col=batch.
//    Same LDS/global reads (A/B frag layouts identical), but C-write becomes
//    ONE packed b64 per nt (4 consecutive n) instead of 4 scattered b16
//    (4x fewer writes + addr comps), and b1 folds into MFMA C-init as an
//    aligned dwordx4 load. Writer swizzle key b&7 = ln&7 = reader key:
//    phase-2 unchanged.
//  - Keep v7 shape: BPB=32, NT=1024, 78KB LDS, 2 blocks/CU = 32 waves/CU.
//  - Keep (validated): du0/du1 hoist, b2-in-C-init, fully-inline, RNE cvt.
// ---------------------------------------------------------------------------

typedef __attribute__((ext_vector_type(8))) _Float16 f16x8;
typedef __attribute__((ext_vector_type(2))) __fp16   fp16v2;   // cvt_pkrtz ret
typedef __attribute__((ext_vector_type(4))) float    f32x4;
typedef __attribute__((ext_vector_type(4))) unsigned int u32x4;

constexpr int   BPB       = 32;       // batch elems per block
constexpr int   NT        = 1024;     // 16 waves
constexpr int   T_STRIDE  = 1664;     // 13 rows * 128 B, chunk-swizzled
constexpr int   WT_OFF    = BPB * T_STRIDE;       // 53248
constexpr int   Y_OFF     = WT_OFF + 192 * 128;   // 77824
constexpr int   LDS_BYTES = Y_OFF + 128;          // 77952 -> 2 blocks/CU

// d_ws layout (bytes)
constexpr int   WS_W1T   = 0;         // 24576: f16 LDS image (pre-swizzled)
constexpr int   WS_W2T   = 24576;     //  4096: f16 [m=32][k=64]
constexpr int   WS_B1    = 28672;     //   256: f32 b1*L2E
constexpr int   WS_B2    = 28928;     //   128: f32 b2*L2E
constexpr int   WS_W3    = 29056;     //   128: f32 W3*LN2

constexpr float L2E = 1.4426950408889634f;
constexpr float LN2 = 0.6931471805599453f;

// PAIRS i/j packed 3 bits per pair (15 pairs)
constexpr unsigned long long I_BITS =
  (0ull<<0)|(0ull<<3)|(0ull<<6)|(0ull<<9)|(0ull<<12)|
  (1ull<<15)|(1ull<<18)|(1ull<<21)|(1ull<<24)|
  (2ull<<27)|(2ull<<30)|(2ull<<33)|
  (3ull<<36)|(3ull<<39)|(4ull<<42);
constexpr unsigned long long J_BITS =
  (1ull<<0)|(2ull<<3)|(3ull<<6)|(4ull<<9)|(5ull<<12)|
  (2ull<<15)|(3ull<<18)|(4ull<<21)|(5ull<<24)|
  (3ull<<27)|(4ull<<30)|(5ull<<33)|
  (4ull<<36)|(5ull<<39)|(5ull<<42);

__device__ __forceinline__ float sp2(float s) {       // log2(1+exp2(s))
  float t = __builtin_amdgcn_exp2f(s);
  return __builtin_amdgcn_logf(1.0f + t);             // v_log_f32 = log2
}

__device__ __forceinline__ __half2 h1pair(__half2 u, __half2 a, __half2 b,
                                          __half2 one2) {
  __half2 s = __hadd2(__hadd2(u, a), b);
  __half2 t = h2exp2(s);                              // |s|<~8 -> safe in f16
  return h2log2(__hadd2(one2, t));
}

// ------------------------- prep: weights -> d_ws ---------------------------
__global__ __launch_bounds__(256)
void prep(const float* __restrict__ W1, const float* __restrict__ b1,
          const float* __restrict__ W2, const float* __restrict__ b2,
          const float* __restrict__ W3, char* __restrict__ ws)
{
  const int t = (int)(blockIdx.x * blockDim.x + threadIdx.x);   // 0..14591
  if (t < 12288) {
    // W1T LDS image: row r = slab*64+n (128B), logical d-chunk dc stored at
    // chunk dc^(r&7); element (r, dl): dg = slab*64+dl, value W1[dg][n]*L2E.
    const int r = t >> 6, dl = t & 63;
    const int slab = r >> 6, n = r & 63;
    const int dg = slab * 64 + dl;
    const float v = W1[(size_t)dg * 64 + n] * L2E;
    *(uint16_t*)(ws + WS_W1T + r * 128 + (((dl >> 3) ^ (r & 7)) << 4)
                 + (dl & 7) * 2) = __half_as_ushort(__float2half(v));
  } else if (t < 14336) {
    const int e = t - 12288;                          // W2 is [k=64][m=32]
    const int k = e >> 5, m = e & 31;
    *(uint16_t*)(ws + WS_W2T + (m * 64 + k) * 2) =
        __half_as_ushort(__float2half(W2[e]));
  } else if (t < 14400) {
    ((float*)(ws + WS_B1))[t - 14336] = b1[t - 14336] * L2E;
  } else if (t < 14432) {
    ((float*)(ws + WS_B2))[t - 14400] = b2[t - 14400] * L2E;
  } else if (t < 14464) {
    ((float*)(ws + WS_W3))[t - 14432] = W3[t - 14432] * LN2;
  }
}

// ------------------------------ main kernel --------------------------------
__global__ __launch_bounds__(NT, 8)
void tb_fused(const float* __restrict__ core, const float* __restrict__ ligs,
              const char* __restrict__ ws,   const float* __restrict__ b3,
              float* __restrict__ out)
{
  extern __shared__ char smem[];
  const int tid  = (int)threadIdx.x;
  const int lane = tid & 63;
  const int ln   = lane & 15;        // fragment column
  const int qd   = lane >> 4;        // fragment quad
  const int swz  = ln & 7;           // XOR chunk swizzle key
  const int wv   = __builtin_amdgcn_readfirstlane(tid >> 6);  // 0..15
  const int b0   = (int)blockIdx.x * BPB;

  float* yred = (float*)(smem + Y_OFF);

  // ---- Phase-1 x-tile prefetch (cold HBM): issue before LDS staging ------
  const int xr = wv >> 1;
  const int mt = wv & 1;
  float4 fA[4];
  if (wv < 14) {
    const float* src = (xr == 0)
        ? (core + (size_t)(b0 + mt * 16 + ln) * 64)
        : (ligs + ((size_t)(b0 + mt * 16 + ln) * 6 + (size_t)(xr - 1)) * 64);
    #pragma unroll
    for (int ks = 0; ks < 2; ++ks) {
      fA[ks * 2 + 0] = *(const float4*)(src + ks * 32 + qd * 8);
      fA[ks * 2 + 1] = *(const float4*)(src + ks * 32 + qd * 8 + 4);
    }
  }

  // ---- stage W1T: plain vector copy of the pre-swizzled f16 image --------
  {
    const uint4* src = (const uint4*)(ws + WS_W1T);   // 1536 chunks of 16B
    uint4*       dst = (uint4*)(smem + WT_OFF);
    dst[tid] = src[tid];
    if (tid < 512) dst[1024 + tid] = src[1024 + tid];
  }
  if (tid < BPB) yred[tid] = 0.0f;
  __syncthreads();                                    // barrier #1: W1T ready

  // ------------- Phase 1: 14 jobs = (xr 0..6) x (mt 0..1), 1 per wave -----
  if (wv < 14) {
    union AFr { f16x8 v; fp16v2 p[4]; } Xf[2];        // x frags (B operand)
    #pragma unroll
    for (int ks = 0; ks < 2; ++ks) {
      Xf[ks].p[0] = __builtin_amdgcn_cvt_pkrtz(fA[ks*2].x, fA[ks*2].y);
      Xf[ks].p[1] = __builtin_amdgcn_cvt_pkrtz(fA[ks*2].z, fA[ks*2].w);
      Xf[ks].p[2] = __builtin_amdgcn_cvt_pkrtz(fA[ks*2+1].x, fA[ks*2+1].y);
      Xf[ks].p[3] = __builtin_amdgcn_cvt_pkrtz(fA[ks*2+1].z, fA[ks*2+1].w);
    }

    const int sl_lo = (xr == 0) ? 0 : 1;
    const int sl_hi = (xr == 0) ? 0 : 2;
    #pragma unroll 1
    for (int sl = sl_lo; sl <= sl_hi; ++sl) {
      const int trow = (xr == 0) ? 0 : ((sl == 1) ? xr : 6 + xr);
      #pragma unroll
      for (int nt = 0; nt < 4; ++nt) {
        // D row = n (H1), col = batch: bias b1 folds into C-init (t=0 only).
        f32x4 c;
        if (trow == 0) {
          c = *(const f32x4*)(ws + WS_B1 + (nt * 16 + qd * 4) * 4);
        } else {
          c = (f32x4){0.f, 0.f, 0.f, 0.f};
        }
        #pragma unroll
        for (int ks = 0; ks < 2; ++ks) {
          // A = W1T frag: row = sl*64+nt*16+ln (row&7 == swz), chunk ks*4+qd
          const f16x8 Wf = *(const f16x8*)(smem + WT_OFF
              + (sl * 64 + nt * 16 + ln) * 128 + ((((ks << 2) + qd) ^ swz) << 4));
          c = __builtin_amdgcn_mfma_f32_16x16x32_f16(Wf, Xf[ks].v, c, 0, 0, 0);
        }
        // c[0..3] = consecutive n = nt*16+qd*4+reg, batch b = mt*16+ln.
        // One b64 write: byte off = trow*128 + ((2nt+(qd>>1))^(b&7))*16 + (qd&1)*8
        union PK { uint2 u; __half2 h[2]; } pk;
        pk.h[0] = __halves2half2(__float2half(c[0]), __float2half(c[1]));
        pk.h[1] = __halves2half2(__float2half(c[2]), __float2half(c[3]));
        *(uint2*)(smem + (size_t)(mt * 16 + ln) * T_STRIDE + trow * 128
                  + ((((nt << 1) + (qd >> 1)) ^ swz) << 4) + (qd & 1) * 8) = pk.u;
      }
    }
  }

  // W2 B-frags + epilogue consts from ws (f16/f32 pre-converted, L2-hot) —
  // overlaps Phase-1 tail.
  f16x8 W2f[2][2];
  #pragma unroll
  for (int nt = 0; nt < 2; ++nt)
    #pragma unroll
    for (int ks = 0; ks < 2; ++ks)
      W2f[nt][ks] = *(const f16x8*)(ws + WS_W2T
          + ((nt * 16 + ln) * 64 + ks * 32 + qd * 8) * 2);
  float b2v[2], w3v[2];
  #pragma unroll
  for (int nt = 0; nt < 2; ++nt) {
    b2v[nt] = ((const float*)(ws + WS_B2))[nt * 16 + ln];
    w3v[nt] = ((const float*)(ws + WS_W3))[nt * 16 + ln];
  }

  __syncthreads();                                    // barrier #2: T ready

  // ------------- Phase 2: 60 units (30 q x 2 mt) over 16 waves ------------
  const int mtw = wv & 1;
  const int qr  = wv >> 1;                            // 0..7
  const __half2 one2 = __float2half2_rn(1.0f);
  const char* Tb = smem + (size_t)(mtw * 16 + ln) * T_STRIDE;
  const int k0 = ((qd)     ^ swz) << 4;               // chunk qd   (ks=0)
  const int k1 = ((qd + 4) ^ swz) << 4;               // chunk qd+4 (ks=1)

  union U4 { u32x4 u; __half2 h[4]; };

  // Row 0 (core pre-activations) is unit-invariant: hoist its 2 reads.
  U4 du0, du1;
  du0.u = *(const u32x4*)(Tb + k0);
  du1.u = *(const u32x4*)(Tb + k1);

  float yacc[4] = {0.f, 0.f, 0.f, 0.f};

  #pragma unroll 2
  for (int t3 = 0; t3 < 4; ++t3) {
    const int q = qr + 8 * t3;
    if (q >= 30) break;                               // wave-uniform
    const int p  = q >> 1;
    const int iv = (int)((I_BITS >> (3 * p)) & 7ull);
    const int jv = (int)((J_BITS >> (3 * p)) & 7ull);
    const int An = (q & 1) ? jv : iv;
    const int Bn = (q & 1) ? iv : jv;
    const char* TA = Tb + (1 + An) * 128;
    const char* TB = Tb + (7 + Bn) * 128;

    U4 da0, db0, da1, db1;
    da0.u = *(const u32x4*)(TA + k0);
    db0.u = *(const u32x4*)(TB + k0);
    da1.u = *(const u32x4*)(TA + k1);
    db1.u = *(const u32x4*)(TB + k1);

    union { f16x8 v; __half2 h[4]; } A0, A1;
    #pragma unroll
    for (int w = 0; w < 4; ++w) A0.h[w] = h1pair(du0.h[w], da0.h[w], db0.h[w], one2);
    #pragma unroll
    for (int w = 0; w < 4; ++w) A1.h[w] = h1pair(du1.h[w], da1.h[w], db1.h[w], one2);

    f32x4 c0 = {b2v[0], b2v[0], b2v[0], b2v[0]};      // bias as C-init
    f32x4 c1 = {b2v[1], b2v[1], b2v[1], b2v[1]};
    c0 = __builtin_amdgcn_mfma_f32_16x16x32_f16(A0.v, W2f[0][0], c0, 0, 0, 0);
    c0 = __builtin_amdgcn_mfma_f32_16x16x32_f16(A1.v, W2f[0][1], c0, 0, 0, 0);
    c1 = __builtin_amdgcn_mfma_f32_16x16x32_f16(A0.v, W2f[1][0], c1, 0, 0, 0);
    c1 = __builtin_amdgcn_mfma_f32_16x16x32_f16(A1.v, W2f[1][1], c1, 0, 0, 0);

    #pragma unroll
    for (int reg = 0; reg < 4; ++reg) {
      yacc[reg] += sp2(c0[reg]) * w3v[0] + sp2(c1[reg]) * w3v[1];
    }
  }

  // reduce over the 16 fragment columns (ln) inside each quad group
  #pragma unroll
  for (int reg = 0; reg < 4; ++reg) {
    float v = yacc[reg];
    v += __shfl_xor(v, 1);
    v += __shfl_xor(v, 2);
    v += __shfl_xor(v, 4);
    v += __shfl_xor(v, 8);
    yacc[reg] = v;
  }
  if (ln == 0) {
    #pragma unroll
    for (int reg = 0; reg < 4; ++reg)
      atomicAdd(&yred[mtw * 16 + qd * 4 + reg], yacc[reg]);
  }
  __syncthreads();
  if (tid < BPB) out[b0 + tid] = 0.5f * yred[tid] + 15.0f * b3[0];
}

extern "C" void kernel_launch(void* const* d_in, const int* in_sizes, int n_in,
                              void* d_out, int out_size, void* d_ws, size_t ws_size,
                              hipStream_t stream) {
  const float* core = (const float*)d_in[0];
  const float* ligs = (const float*)d_in[1];
  const float* W1   = (const float*)d_in[2];
  const float* b1   = (const float*)d_in[3];
  const float* W2   = (const float*)d_in[4];
  const float* b2   = (const float*)d_in[5];
  const float* W3   = (const float*)d_in[6];
  const float* b3   = (const float*)d_in[7];
  float* out = (float*)d_out;
  char*  ws  = (char*)d_ws;                 // 29 KB used; fill is sunk cost

  const int B = in_sizes[0] / 64;           // 32768
  const int grid = B / BPB;                 // 1024

  prep<<<dim3(57), dim3(256), 0, stream>>>(W1, b1, W2, b2, W3, ws);

  (void)hipFuncSetAttribute((const void*)tb_fused,
                            hipFuncAttributeMaxDynamicSharedMemorySize, LDS_BYTES);
  tb_fused<<<dim3(grid), dim3(NT), LDS_BYTES, stream>>>(
      core, ligs, ws, b3, out);
}